// Round 7
// baseline (306.735 us; speedup 1.0000x reference)
//
#include <hip/hip_runtime.h>

#define IMG 512
#define OUT_C 64         // output cols per block
#define STRIP_R 128      // output rows per block
#define CHUNK 16         // output rows per iteration
#define NITER (STRIP_R / CHUNK)
#define HALO 5
#define VS 88            // vb row stride in halfs (176B -> 2-way-free banks)
#define NT 256
#define NSLOTS 64

typedef _Float16 f16x8 __attribute__((ext_vector_type(8)));
typedef _Float16 h2    __attribute__((ext_vector_type(2)));
typedef float    f32x4 __attribute__((ext_vector_type(4)));

static constexpr float GWf[11] = {
    0.00102838f, 0.00759876f, 0.03600077f, 0.10936053f, 0.21300556f,
    0.26601170f, 0.21300556f, 0.10936053f, 0.03600077f, 0.00759876f,
    0.00102838f };

// Banded weight fragment W[i][k] = w[k-i]; same table is the vertical A-frag
// and horizontal B-frag (mapping HW-verified by R2/R3/R4/R6 absmax=0:
// lane(fj,fg) elem b <-> k = 8*fg+b; i/j = fj).
struct WTab { alignas(16) _Float16 v[4][16][8]; };
static constexpr WTab make_wtab() {
    WTab t{};
    for (int g = 0; g < 4; ++g)
        for (int j = 0; j < 16; ++j)
            for (int b = 0; b < 8; ++b) {
                const int d = 8 * g + b - j;
                t.v[g][j][b] = (d >= 0 && d <= 10) ? (_Float16)GWf[d]
                                                   : (_Float16)0.f;
            }
    return t;
}
__device__ constexpr WTab WT = make_wtab();

// Only LDS: vertical-conv output (the vert->horiz transpose) + reduce scratch.
struct SMem {
    _Float16 vb[4][CHUNK][VS];   // 11264 B
    float red[4];
};                               // 11280 B

__device__ __forceinline__ h2 cvt_pk(float a, float b) {
#if __has_builtin(__builtin_amdgcn_cvt_pkrtz)
    auto r = __builtin_amdgcn_cvt_pkrtz(a, b);   // __fp16x2, bit-identical
    union { decltype(r) i; h2 o; } u; u.i = r;
    return u.o;
#else
    h2 r; r[0] = (_Float16)a; r[1] = (_Float16)b; return r;
#endif
}

// Issue loads for one tile's 32-row window (rows ytop-5 .. ytop+26) into regs.
// Zero-fill outside the image == conv zero padding (k>=26 rows are harmless
// real values; their weights are 0 in WT).
__device__ __forceinline__ void load_win(
    int tl, int ytop, int c0, size_t pbase,
    const float* __restrict__ den, const float* __restrict__ cln,
    int fj, int fg, float Px[8], float Py[8])
{
    const int gc = c0 - HALO + tl * 16 + fj;
    const bool colok = (unsigned)gc < IMG;
    const int rbase = ytop - HALO + 8 * fg;
#pragma unroll
    for (int b = 0; b < 8; ++b) {
        const int gr = rbase + b;
        const bool ok = colok && ((unsigned)gr < IMG);
        float xv = 0.f, yv = 0.f;
        if (ok) {
            const size_t idx = pbase + (size_t)gr * IMG + gc;
            xv = den[idx]; yv = cln[idx];
        }
        Px[b] = xv; Py[b] = yv;
    }
}

union Frag { f16x8 v; h2 p[4]; };

__device__ __forceinline__ void pack_all(const float Px[8], const float Py[8],
                                         Frag& fx, Frag& fy, Frag& fq, Frag& fp) {
#pragma unroll
    for (int bb = 0; bb < 4; ++bb) {
        const float x0 = fminf(fmaxf(Px[2 * bb], 0.f), 1.f);     // v_med3
        const float x1 = fminf(fmaxf(Px[2 * bb + 1], 0.f), 1.f);
        const float ya = fminf(fmaxf(Py[2 * bb], 0.f), 1.f);
        const float yb = fminf(fmaxf(Py[2 * bb + 1], 0.f), 1.f);
        const h2 xh = cvt_pk(x0, x1);
        const h2 yh = cvt_pk(ya, yb);
        fx.p[bb] = xh;
        fy.p[bb] = yh;
        fq.p[bb] = xh * xh + yh * yh;
        fp.p[bb] = xh * yh;
    }
}

// Pack only channel `ch` (wave-uniform) from a window.
__device__ __forceinline__ void pack_ch(const float Px[8], const float Py[8],
                                        int ch, Frag& f) {
#pragma unroll
    for (int bb = 0; bb < 4; ++bb) {
        const float x0 = fminf(fmaxf(Px[2 * bb], 0.f), 1.f);
        const float x1 = fminf(fmaxf(Px[2 * bb + 1], 0.f), 1.f);
        const float ya = fminf(fmaxf(Py[2 * bb], 0.f), 1.f);
        const float yb = fminf(fmaxf(Py[2 * bb + 1], 0.f), 1.f);
        const h2 xh = cvt_pk(x0, x1);
        const h2 yh = cvt_pk(ya, yb);
        if (ch == 0)      f.p[bb] = xh;
        else if (ch == 1) f.p[bb] = yh;
        else if (ch == 2) f.p[bb] = xh * xh + yh * yh;
        else              f.p[bb] = xh * yh;
    }
}

__global__ __launch_bounds__(NT, 6)
void ssim_mfma(const float* __restrict__ den, const float* __restrict__ cln,
               double* __restrict__ slots) {
    __shared__ SMem sm;

    const int t    = threadIdx.x;
    const int lane = t & 63;
    const int w    = t >> 6;
    const int fj   = lane & 15;
    const int fg   = lane >> 4;

    // XCD-chunked swizzle (grid % 8 == 0)
    const int bid = blockIdx.x;
    const int chunk = gridDim.x >> 3;
    const int vid = (bid & 7) * chunk + (bid >> 3);

    const int rs    = vid & 3;          // 4 row strips of 128
    const int cs    = (vid >> 2) & 7;   // 8 col strips of 64
    const int plane = vid >> 5;         // 96 planes
    const int c0 = cs * OUT_C;
    const int y0 = rs * STRIP_R;
    const size_t pbase = (size_t)plane * (IMG * IMG);

    const f16x8 wf = *reinterpret_cast<const f16x8*>(WT.v[fg][fj]);
    const f32x4 zero4 = {0.f, 0.f, 0.f, 0.f};

    // Register prefetch state: own tile (w) + shared halo tile (4).
    float Px[8], Py[8], P4x[8], P4y[8];
    load_win(w, y0, c0, pbase, den, cln, fj, fg, Px, Py);
    load_win(4, y0, c0, pbase, den, cln, fj, fg, P4x, P4y);

    float sacc = 0.f;
    for (int it = 0; it < NITER; ++it) {
        const int yo = y0 + CHUNK * it;

        // ---- pack current-iteration fragments (consumes P, frees it) ----
        Frag fx, fy, fq, fp, f4;
        pack_all(Px, Py, fx, fy, fq, fp);
        pack_ch(P4x, P4y, w, f4);   // wave w owns channel w of halo tile

        // ---- issue next-iteration loads (latency hides under this iter) --
        if (it < NITER - 1) {
            load_win(w, yo + CHUNK, c0, pbase, den, cln, fj, fg, Px, Py);
            load_win(4, yo + CHUNK, c0, pbase, den, cln, fj, fg, P4x, P4y);
        }

        // ---- vertical conv via MFMA (5 per wave) ----
        const f32x4 a0 = __builtin_amdgcn_mfma_f32_16x16x32_f16(wf, fx.v, zero4, 0, 0, 0);
        const f32x4 a1 = __builtin_amdgcn_mfma_f32_16x16x32_f16(wf, fy.v, zero4, 0, 0, 0);
        const f32x4 a2 = __builtin_amdgcn_mfma_f32_16x16x32_f16(wf, fq.v, zero4, 0, 0, 0);
        const f32x4 a3 = __builtin_amdgcn_mfma_f32_16x16x32_f16(wf, fp.v, zero4, 0, 0, 0);
        const f32x4 a4 = __builtin_amdgcn_mfma_f32_16x16x32_f16(wf, f4.v, zero4, 0, 0, 0);

        __syncthreads();   // previous horizontal finished reading vb

        const int cc = w * 16 + fj;
#pragma unroll
        for (int b = 0; b < 4; ++b) {
            const int r = 4 * fg + b;   // D: col=lane&15, row=4*(lane>>4)+b
            sm.vb[0][r][cc] = (_Float16)a0[b];
            sm.vb[1][r][cc] = (_Float16)a1[b];
            sm.vb[2][r][cc] = (_Float16)a2[b];
            sm.vb[3][r][cc] = (_Float16)a3[b];
            sm.vb[w][r][64 + fj] = (_Float16)a4[b];   // halo tile, channel w
        }
        __syncthreads();

        // ---- horizontal conv via MFMA (out-tile m = w) + SSIM ----
        f32x4 d[4];
#pragma unroll
        for (int ch = 0; ch < 4; ++ch) {
            const f16x8 af = *reinterpret_cast<const f16x8*>(
                &sm.vb[ch][fj][w * 16 + 8 * fg]);
            d[ch] = __builtin_amdgcn_mfma_f32_16x16x32_f16(af, wf, zero4, 0, 0, 0);
        }
#pragma unroll
        for (int b = 0; b < 4; ++b) {
            const float C1 = 1e-4f, C2 = 9e-4f;
            const float mu1 = d[0][b], mu2 = d[1][b];
            const float qb  = d[2][b], pb  = d[3][b];
            const float mu1s = mu1 * mu1, mu2s = mu2 * mu2, mu12 = mu1 * mu2;
            const float ssum = qb - mu1s - mu2s;
            const float s12  = pb - mu12;
            const float num = fmaf(2.f, mu12, C1) * fmaf(2.f, s12, C2);
            const float dnm = (mu1s + mu2s + C1) * (ssum + C2);
            sacc = fmaf(num, __builtin_amdgcn_rcpf(dnm), sacc);
        }
    }

    // ---- block reduction, one f64 atomic per block into a hashed slot ----
#pragma unroll
    for (int off = 32; off > 0; off >>= 1)
        sacc += __shfl_down(sacc, off, 64);
    if (lane == 0) sm.red[w] = sacc;
    __syncthreads();
    if (t == 0) {
        const float s = sm.red[0] + sm.red[1] + sm.red[2] + sm.red[3];
        atomicAdd(&slots[(size_t)(bid & (NSLOTS - 1)) * 8], (double)s);
    }
}

__global__ void ssim_finalize(const double* __restrict__ slots,
                              float* __restrict__ out, double inv_n) {
    double s = 0.0;
    for (int i = 0; i < NSLOTS; ++i) s += slots[i * 8];
    out[0] = 1.0f - (float)(s * inv_n);
}

extern "C" void kernel_launch(void* const* d_in, const int* in_sizes, int n_in,
                              void* d_out, int out_size, void* d_ws,
                              size_t ws_size, hipStream_t stream) {
    const float* den = (const float*)d_in[0];
    const float* cln = (const float*)d_in[1];
    float* out = (float*)d_out;
    double* slots = (double*)d_ws;

    (void)hipMemsetAsync(d_ws, 0, NSLOTS * 64, stream);

    const int n = in_sizes[0];                  // 32*3*512*512 elements
    const int planes = n / (IMG * IMG);         // 96
    dim3 grid(planes * (IMG / STRIP_R) * (IMG / OUT_C));   // 96*4*8 = 3072
    ssim_mfma<<<grid, NT, 0, stream>>>(den, cln, slots);
    ssim_finalize<<<1, 1, 0, stream>>>(slots, out, 1.0 / (double)n);
}